// Round 4
// baseline (9807.982 us; speedup 1.0000x reference)
//
#include <hip/hip_runtime.h>
#include <stdint.h>
#include <stddef.h>

typedef __attribute__((ext_vector_type(8))) _Float16 half8;
typedef __attribute__((ext_vector_type(8))) unsigned short ushort8;
typedef __attribute__((ext_vector_type(4))) float f4;

namespace {
constexpr int kSteps = 255;   // reference iterates t = 0 .. T-2
constexpr int KTOT = 1152;    // 1024 (h) + 128 (x)

// workspace layout (bytes); total ~45 MB
// h layout: [group(4)][ub(64)][row(128)][u(16)] fp16 -> block-contiguous 4KB slices
constexpr size_t OFF_H0   = 0;                                   // 1 MB  h ping
constexpr size_t OFF_CNT  = (size_t)1 << 20;                     // 4 KB  barrier counters
constexpr size_t OFF_H1   = ((size_t)1 << 20) + 4096;            // 1 MB  h pong
constexpr size_t OFF_BSUM = OFF_H1 + ((size_t)1 << 20);          // 16 KB b_ih+b_hh (fp32)
constexpr size_t OFF_WCAT = OFF_BSUM + 16384;                    // 9.4 MB fp16 [4096][1152]
constexpr size_t OFF_XT   = OFF_WCAT + (size_t)4096 * KTOT * 2;  // 33.4 MB fp16 [255][512][128]
}

__device__ __forceinline__ unsigned short f2h(float f) {
  _Float16 h = (_Float16)f;
  return __builtin_bit_cast(unsigned short, h);
}
__device__ __forceinline__ float h2f(unsigned short s) {
  return (float)__builtin_bit_cast(_Float16, s);
}

// counted-vmcnt barrier (T3/T4): my newest 4 staging loads may stay in flight
#define KBAR(N) do { \
    asm volatile("s_waitcnt vmcnt(" N ") lgkmcnt(0)\n\ts_barrier" ::: "memory"); \
    __builtin_amdgcn_sched_barrier(0); \
  } while (0)

// ---------- prep 1: Wcat fp16 + bsum ----------
__global__ void prep_wcat(const float* __restrict__ Wih, const float* __restrict__ Whh,
                          const float* __restrict__ bih, const float* __restrict__ bhh,
                          char* __restrict__ ws) {
  if (blockIdx.x < 2304) {
    unsigned gid = blockIdx.x * 256 + threadIdx.x;
    unsigned row = gid / 144, cc = gid % 144;
    const float* src = (cc < 128) ? (Whh + (size_t)row * 1024 + (size_t)cc * 8)
                                  : (Wih + (size_t)row * 128 + (size_t)(cc - 128) * 8);
    ushort8 o;
#pragma unroll
    for (int j = 0; j < 8; j++) o[j] = f2h(src[j]);
    *(ushort8*)((unsigned short*)(ws + OFF_WCAT) + (size_t)row * KTOT + cc * 8) = o;
  } else {
    int i = (blockIdx.x - 2304) * 256 + threadIdx.x;
    ((float*)(ws + OFF_BSUM))[i] = bih[i] + bhh[i];
  }
}

// ---------- prep 2: xT[t][b][i] = fp16(x[b][i][t]) ----------
__global__ void prep_xt(const float* __restrict__ x, char* __restrict__ ws) {
  unsigned short* xT = (unsigned short*)(ws + OFF_XT);
  __shared__ unsigned short tile[128][72];
  const int b = blockIdx.x >> 2;
  const int t0 = (blockIdx.x & 3) * 64;
  const int wv = threadIdx.x >> 6, tl = threadIdx.x & 63;
  if (t0 + tl < 255) {
#pragma unroll
    for (int ii = 0; ii < 32; ii++) {
      int i = wv + ii * 4;
      tile[i][tl] = f2h(x[((size_t)b * 128 + i) * 256 + t0 + tl]);
    }
  }
  __syncthreads();
  const int tl2 = threadIdx.x >> 4, ic = threadIdx.x & 15;
#pragma unroll
  for (int pp = 0; pp < 4; pp++) {
    int tloc = pp * 16 + tl2;
    int t = t0 + tloc;
    if (t < 255) {
      ushort8 v;
#pragma unroll
      for (int j = 0; j < 8; j++) v[j] = tile[ic * 8 + j][tloc];
      *(ushort8*)&xT[((size_t)t * 512 + b) * 128 + ic * 8] = v;
    }
  }
}

// ---------- persistent LSTM kernel ----------
// grid 256 = 4 groups (128 batch rows) x 64 unit-blocks (16 units). 8 waves = 2M x 2N x 2K.
// K pipeline: 8 chunks of 128 cols, 4 x 32KB LDS bufs (mod-4), stage j+2 during compute j.
__global__ __launch_bounds__(512, 1) void lstm_persist(char* __restrict__ ws) {
  const unsigned short* __restrict__ wcat = (const unsigned short*)(ws + OFF_WCAT);
  const float* __restrict__ bsum = (const float*)(ws + OFF_BSUM);
  const unsigned short* __restrict__ xT = (const unsigned short*)(ws + OFF_XT);
  unsigned short* h0 = (unsigned short*)(ws + OFF_H0);
  unsigned short* h1 = (unsigned short*)(ws + OFF_H1);

  __shared__ __align__(16) unsigned short Ab[4][16384];   // 4 x 32KB; Ab[0] doubles as reduce scratch

  const int tid = threadIdx.x;
  const int lane = tid & 63;
  const int w = tid >> 6;
  const int wk = w & 1;           // K parity (even/odd 64-col halves of each chunk)
  const int wm = (w >> 1) & 1;    // M half
  const int wn = (w >> 2) & 1;    // N half
  const int l15 = lane & 15, l4 = lane >> 4, g = lane & 3, p = lane & 3;
  const int gblk = blockIdx.x >> 6;
  const int cblk = blockIdx.x & 63;
  const int B0 = gblk * 128;
  const int U0 = cblk * 16;
  int* cntp = (int*)(ws + OFF_CNT) + gblk * 16;

  // ---- weight fragments -> registers (persist whole kernel) ----
  half8 bf[16][2];    // h chunks c=0..7, s=0..1
  half8 bfx[2][2];    // x, s=0..1
  float bs[2];
#pragma unroll
  for (int nf = 0; nf < 2; nf++) {
    int u = wn * 8 + nf * 4 + (l15 >> 2);
    int R = g * 1024 + U0 + u;                  // gate order i,f,g,o in 1024-chunks
    bs[nf] = bsum[R];
#pragma unroll
    for (int c = 0; c < 8; c++)
#pragma unroll
      for (int s = 0; s < 2; s++)
        bf[c * 2 + s][nf] = *(const half8*)&wcat[(size_t)R * KTOT + c * 128 + wk * 64 + s * 32 + l4 * 8];
#pragma unroll
    for (int s = 0; s < 2; s++)
      bfx[s][nf] = *(const half8*)&wcat[(size_t)R * KTOT + 1024 + wk * 64 + s * 32 + l4 * 8];
  }
  const float bseed0 = (wk == 0) ? bs[0] : 0.f;   // only one K-half seeds the bias
  const float bseed1 = (wk == 0) ? bs[1] : 0.f;

  // ---- staging constants: 4 global_load_lds per wave per 32KB chunk ----
  // LDS slot (1KB) s = w*4+i; lane ln writes bytes s*1024+ln*16 = row (s*4+ln/16), colchunk ln&15.
  // Content must be G(row, c8l ^ (row&7)) so swizzled ds_reads land conflict-free.
  int ldsoff[4]; int hoffc[4]; int xoff[4];
#pragma unroll
  for (int i = 0; i < 4; i++) {
    int s = w * 4 + i;
    int row = s * 4 + (lane >> 4);
    int c8 = (lane & 15) ^ (row & 7);
    ldsoff[i] = s * 1024;                                     // wave-uniform byte base
    hoffc[i] = ((gblk * 64 + (c8 >> 1)) * 128 + row) * 16 + (c8 & 1) * 8;  // + c*16384 per chunk
    xoff[i] = (B0 + row) * 128 + c8 * 8;
  }
  // A-fragment ds_read offsets (bytes), swizzle-matched
  int aofs[4][2];
#pragma unroll
  for (int m = 0; m < 4; m++)
#pragma unroll
    for (int s = 0; s < 2; s++) {
      int rowl = wm * 64 + m * 16 + l15;
      int c8r = wk * 8 + s * 4 + l4;
      aofs[m][s] = rowl * 256 + ((c8r ^ (rowl & 7)) * 16);
    }

  f4 acc[4][2];

  auto STAGE_H = [&](int c, const unsigned short* hsrc) {
#pragma unroll
    for (int i = 0; i < 4; i++)
      __builtin_amdgcn_global_load_lds(
          (const __attribute__((address_space(1))) void*)(hsrc + hoffc[i] + c * 16384),
          (__attribute__((address_space(3))) void*)((char*)&Ab[c & 3][0] + ldsoff[i]),
          16, 0, 0);
  };
  auto STAGE_X = [&](const unsigned short* xslab) {
#pragma unroll
    for (int i = 0; i < 4; i++)
      __builtin_amdgcn_global_load_lds(
          (const __attribute__((address_space(1))) void*)(xslab + xoff[i]),
          (__attribute__((address_space(3))) void*)((char*)&Ab[3][0] + ldsoff[i]),
          16, 0, 0);
  };
  auto COMPUTE = [&](const unsigned short* buf, const half8 frag[][2]) {
    const char* base = (const char*)buf;
#pragma unroll
    for (int s = 0; s < 2; s++) {
      half8 a[4];
#pragma unroll
      for (int m = 0; m < 4; m++) a[m] = *(const half8*)(base + aofs[m][s]);
#pragma unroll
      for (int m = 0; m < 4; m++)
#pragma unroll
        for (int nf = 0; nf < 2; nf++)
          acc[m][nf] = __builtin_amdgcn_mfma_f32_16x16x32_f16(a[m], frag[s][nf],
                                                              acc[m][nf], 0, 0, 0);
    }
  };

  float creg[2][2] = {{0.f, 0.f}, {0.f, 0.f}};

#pragma unroll 1
  for (int t = 0; t < kSteps; t++) {
    const unsigned short* hsrc = (t & 1) ? h1 : h0;
    unsigned short* hdst = (t & 1) ? h0 : h1;
    const unsigned short* xslab = xT + (size_t)t * (512 * 128);

#pragma unroll
    for (int m = 0; m < 4; m++) {
      acc[m][0] = (f4){bseed0, bseed0, bseed0, bseed0};
      acc[m][1] = (f4){bseed1, bseed1, bseed1, bseed1};
    }

    STAGE_X(xslab);              // x loads fly while we wait on the group barrier

    if (tid == 0) {              // all 64 blocks of this group finished step t-1?
      int target = 64 * t;
      int guard = 1 << 18;
      while (guard--) {
        int c;
        asm volatile("global_load_dword %0, %1, off sc0 sc1\n\ts_waitcnt vmcnt(0)"
                     : "=v"(c) : "v"(cntp) : "memory");
        if (c >= target) break;
        __builtin_amdgcn_s_sleep(2);
      }
      // ONE acquire (L2 inv) per block per step, not per poll
      int f = __hip_atomic_load(cntp, __ATOMIC_ACQUIRE, __HIP_MEMORY_SCOPE_AGENT);
      asm volatile("" :: "v"(f));
    }
    __syncthreads();             // joins + drains x staging (vmcnt 0)

    STAGE_H(0, hsrc);
    STAGE_H(1, hsrc);
    COMPUTE(&Ab[3][0], bfx);     // x contribution overlaps h-stage latency
    KBAR("4");                   // chunk 0 resident everywhere; chunk 1 in flight

#pragma unroll
    for (int j = 0; j < 8; j++) {
      if (j < 6) STAGE_H(j + 2, hsrc);
      COMPUTE(&Ab[j & 3][0], &bf[j * 2]);
      if (j < 6) KBAR("4"); else KBAR("0");
    }

    // ---- cross-wave K reduction through LDS (Ab[0], 32KB) ----
    float* red = (float*)&Ab[0][0];
    {
      const int myoff = w * 1024 + lane * 4;
#pragma unroll
      for (int mi = 0; mi < 2; mi++)
#pragma unroll
        for (int nf = 0; nf < 2; nf++) {
          f4 v = wk ? acc[mi][nf] : acc[2 + mi][nf];       // partner's m-half
          *(f4*)&red[myoff + (mi * 2 + nf) * 256] = v;
        }
    }
    __syncthreads();
    {
      const int proff = (w ^ 1) * 1024 + lane * 4;
#pragma unroll
      for (int mi = 0; mi < 2; mi++)
#pragma unroll
        for (int nf = 0; nf < 2; nf++) {
          f4 mine = wk ? acc[2 + mi][nf] : acc[mi][nf];
          f4 oth = *(const f4*)&red[proff + (mi * 2 + nf) * 256];
          f4 gs = mine + oth;
          float sc = (g == 2) ? 2.f : 1.f;
          float aa = (g == 2) ? 2.f : 1.f;
          float ab = (g == 2) ? -1.f : 0.f;
          float a0 = aa / (1.f + __expf(-sc * gs[0])) + ab;
          float a1 = aa / (1.f + __expf(-sc * gs[1])) + ab;
          float a2 = aa / (1.f + __expf(-sc * gs[2])) + ab;
          float a3 = aa / (1.f + __expf(-sc * gs[3])) + ab;
          float s0 = (p & 1) ? a0 : a1;
          float s1 = (p & 1) ? a2 : a3;
          s0 = __shfl_xor(s0, 1); s1 = __shfl_xor(s1, 1);
          float A0 = (p & 1) ? s0 : a0;
          float A1 = (p & 1) ? a1 : s0;
          float A2 = (p & 1) ? s1 : a2;
          float A3 = (p & 1) ? a3 : s1;
          float t0 = (p & 2) ? A0 : A2;
          float t1 = (p & 2) ? A1 : A3;
          t0 = __shfl_xor(t0, 2); t1 = __shfl_xor(t1, 2);
          float q0 = (p & 2) ? t0 : A0;   // i
          float q1 = (p & 2) ? t1 : A1;   // f
          float q2 = (p & 2) ? A2 : t0;   // g~
          float q3 = (p & 2) ? A3 : t1;   // o
          float cn = q1 * creg[mi][nf] + q0 * q2;
          creg[mi][nf] = cn;
          float th = 2.f / (1.f + __expf(-2.f * cn)) - 1.f;
          float hv = q3 * th;
          int m = wk * 2 + mi;
          int rowl = wm * 64 + m * 16 + l4 * 4 + p;
          int coll = wn * 8 + nf * 4 + ((lane >> 2) & 3);
          // block-contiguous slice: [(gblk*64+cblk)*128 + rowl][coll]
          hdst[(size_t)((gblk * 64 + cblk) * 128 + rowl) * 16 + coll] = f2h(hv);
        }
    }
    __syncthreads();             // drains h stores (vmcnt 0) before arrival
    if (tid == 0)
      __hip_atomic_fetch_add(cntp, 1, __ATOMIC_RELEASE, __HIP_MEMORY_SCOPE_AGENT);
  }
}

// ---------- FC: out = h_last @ W_fc^T + b_fc ----------
__global__ void fc_kernel(const char* __restrict__ ws, const float* __restrict__ Wfc,
                          const float* __restrict__ bfc, float* __restrict__ out) {
  const unsigned short* h = (const unsigned short*)(ws + OFF_H1);  // t=254 writes h1
  int o = threadIdx.x & 127;
  int b = blockIdx.x * 2 + (threadIdx.x >> 7);
  const float* wrow = Wfc + (size_t)o * 1024;
  float acc = bfc[o];
  int gb = b >> 7, rb = b & 127;
#pragma unroll 4
  for (int k = 0; k < 1024; k += 8) {
    ushort8 hv = *(const ushort8*)&h[((size_t)(gb * 64 + (k >> 4)) * 128 + rb) * 16 + (k & 15)];
    f4 w0 = *(const f4*)&wrow[k];
    f4 w1 = *(const f4*)&wrow[k + 4];
#pragma unroll
    for (int j = 0; j < 4; j++) acc += h2f(hv[j]) * w0[j];
#pragma unroll
    for (int j = 0; j < 4; j++) acc += h2f(hv[4 + j]) * w1[j];
  }
  out[(size_t)b * 128 + o] = acc;
}

extern "C" void kernel_launch(void* const* d_in, const int* in_sizes, int n_in,
                              void* d_out, int out_size, void* d_ws, size_t ws_size,
                              hipStream_t stream) {
  const float* x   = (const float*)d_in[0];
  const float* Wih = (const float*)d_in[1];
  const float* Whh = (const float*)d_in[2];
  const float* bih = (const float*)d_in[3];
  const float* bhh = (const float*)d_in[4];
  const float* Wfc = (const float*)d_in[5];
  const float* bfc = (const float*)d_in[6];
  char* ws = (char*)d_ws;

  hipMemsetAsync(ws + OFF_H0, 0, ((size_t)1 << 20) + 4096, stream);
  prep_wcat<<<2320, 256, 0, stream>>>(Wih, Whh, bih, bhh, ws);
  prep_xt<<<2048, 256, 0, stream>>>(x, ws);
  lstm_persist<<<256, 512, 0, stream>>>(ws);
  fc_kernel<<<256, 256, 0, stream>>>(ws, Wfc, bfc, (float*)d_out);
}

// Round 5
// 5367.200 us; speedup vs baseline: 1.8274x; 1.8274x over previous
//
#include <hip/hip_runtime.h>
#include <stdint.h>
#include <stddef.h>

typedef __attribute__((ext_vector_type(8))) _Float16 half8;
typedef __attribute__((ext_vector_type(8))) unsigned short ushort8;
typedef __attribute__((ext_vector_type(4))) float f4;

namespace {
constexpr int kSteps = 255;   // reference iterates t = 0 .. T-2
constexpr int KTOT = 1152;    // 1024 (h) + 128 (x)

// workspace layout (bytes); total ~45 MB
// h layout: [group(4)][ub(64)][row(128)][u(16)] fp16 -> block-contiguous 4KB slices
constexpr size_t OFF_H0   = 0;                                   // 1 MB  h ping
constexpr size_t OFF_CNT  = (size_t)1 << 20;                     // 4 KB  barrier counters
constexpr size_t OFF_H1   = ((size_t)1 << 20) + 4096;            // 1 MB  h pong
constexpr size_t OFF_BSUM = OFF_H1 + ((size_t)1 << 20);          // 16 KB b_ih+b_hh (fp32)
constexpr size_t OFF_WCAT = OFF_BSUM + 16384;                    // 9.4 MB fp16 [4096][1152]
constexpr size_t OFF_XT   = OFF_WCAT + (size_t)4096 * KTOT * 2;  // 33.4 MB fp16 [255][512][128]
}

__device__ __forceinline__ unsigned short f2h(float f) {
  _Float16 h = (_Float16)f;
  return __builtin_bit_cast(unsigned short, h);
}
__device__ __forceinline__ float h2f(unsigned short s) {
  return (float)__builtin_bit_cast(_Float16, s);
}

// ---------- prep 1: Wcat fp16 + bsum ----------
__global__ void prep_wcat(const float* __restrict__ Wih, const float* __restrict__ Whh,
                          const float* __restrict__ bih, const float* __restrict__ bhh,
                          char* __restrict__ ws) {
  if (blockIdx.x < 2304) {
    unsigned gid = blockIdx.x * 256 + threadIdx.x;
    unsigned row = gid / 144, cc = gid % 144;
    const float* src = (cc < 128) ? (Whh + (size_t)row * 1024 + (size_t)cc * 8)
                                  : (Wih + (size_t)row * 128 + (size_t)(cc - 128) * 8);
    ushort8 o;
#pragma unroll
    for (int j = 0; j < 8; j++) o[j] = f2h(src[j]);
    *(ushort8*)((unsigned short*)(ws + OFF_WCAT) + (size_t)row * KTOT + cc * 8) = o;
  } else {
    int i = (blockIdx.x - 2304) * 256 + threadIdx.x;
    ((float*)(ws + OFF_BSUM))[i] = bih[i] + bhh[i];
  }
}

// ---------- prep 2: xT[t][b][i] = fp16(x[b][i][t]) ----------
__global__ void prep_xt(const float* __restrict__ x, char* __restrict__ ws) {
  unsigned short* xT = (unsigned short*)(ws + OFF_XT);
  __shared__ unsigned short tile[128][72];
  const int b = blockIdx.x >> 2;
  const int t0 = (blockIdx.x & 3) * 64;
  const int wv = threadIdx.x >> 6, tl = threadIdx.x & 63;
  if (t0 + tl < 255) {
#pragma unroll
    for (int ii = 0; ii < 32; ii++) {
      int i = wv + ii * 4;
      tile[i][tl] = f2h(x[((size_t)b * 128 + i) * 256 + t0 + tl]);
    }
  }
  __syncthreads();
  const int tl2 = threadIdx.x >> 4, ic = threadIdx.x & 15;
#pragma unroll
  for (int pp = 0; pp < 4; pp++) {
    int tloc = pp * 16 + tl2;
    int t = t0 + tloc;
    if (t < 255) {
      ushort8 v;
#pragma unroll
      for (int j = 0; j < 8; j++) v[j] = tile[ic * 8 + j][tloc];
      *(ushort8*)&xT[((size_t)t * 512 + b) * 128 + ic * 8] = v;
    }
  }
}

// counted-vmcnt + barrier (T3/T4)
#define WAITBAR(N) do { \
    asm volatile("s_waitcnt vmcnt(" #N ") lgkmcnt(0)\n\ts_barrier" ::: "memory"); \
    __builtin_amdgcn_sched_barrier(0); \
  } while (0)

// ---------- persistent LSTM kernel ----------
// grid 256 = 4 groups (128 rows) x 64 unit-blocks (16 units). 8 waves = 4K x 2N.
// Wave tile: M=128, N=32, K=288 (k-slice kk==wk mod 4 within each 128-col chunk).
// Weights: bf[9][2] = 72 VGPR. acc[8][2] f4 = 64 VGPR. Zero scratch by construction.
__global__ __launch_bounds__(512, 1) void lstm_persist(char* __restrict__ ws) {
  const unsigned short* __restrict__ wcat = (const unsigned short*)(ws + OFF_WCAT);
  const float* __restrict__ bsum = (const float*)(ws + OFF_BSUM);
  const unsigned short* __restrict__ xT = (const unsigned short*)(ws + OFF_XT);
  unsigned short* h0 = (unsigned short*)(ws + OFF_H0);
  unsigned short* h1 = (unsigned short*)(ws + OFF_H1);

  __shared__ __align__(16) unsigned short Ab[4][16384];   // 4 x 32KB chunk bufs / reduce scratch

  const int tid = threadIdx.x;
  const int lane = tid & 63;
  const int w = tid >> 6;
  const int wk = w & 3;           // K group (k-slice parity mod 4)
  const int wn = w >> 2;          // N half
  const int l15 = lane & 15, l4 = lane >> 4;
  const int gblk = blockIdx.x >> 6;
  const int cblk = blockIdx.x & 63;
  const int B0 = gblk * 128;
  const int U0 = cblk * 16;
  int* cntp = (int*)(ws + OFF_CNT) + gblk * 16;

  // ---- weight fragments -> registers (col n = wn*32+nf*16+l15 -> unit n>>2, gate n&3) ----
  half8 bf[9][2];
  float bs[2];
#pragma unroll
  for (int nf = 0; nf < 2; nf++) {
    int u = wn * 8 + nf * 4 + (l15 >> 2);
    int R = (l15 & 3) * 1024 + U0 + u;          // PyTorch gate order i,f,g,o
    bs[nf] = bsum[R];
#pragma unroll
    for (int c = 0; c < 9; c++)
      bf[c][nf] = *(const half8*)&wcat[(size_t)R * KTOT + c * 128 + wk * 32 + l4 * 8];
  }
  const float bseed0 = (wk == 0) ? bs[0] : 0.f;
  const float bseed1 = (wk == 0) ? bs[1] : 0.f;

  // ---- staging: 32 slots of 1KB per 32KB chunk; slot s = w*4+i (wave-uniform LDS base) ----
  // LDS (row, c16) holds G(row, c16 ^ (row&7)); source pre-inverse-swizzled (rule #21).
  int hoffc[4], xoff[4];
#pragma unroll
  for (int i = 0; i < 4; i++) {
    int s = w * 4 + i;
    int row = s * 4 + (lane >> 4);
    int cg = (lane & 15) ^ (row & 7);
    hoffc[i] = (cg >> 1) * 2048 + row * 16 + (cg & 1) * 8;   // + c*16384, + group base
    xoff[i] = (B0 + row) * 128 + cg * 8;
  }
  // A ds_read: row = m*16+l15, c16 = (wk*4+l4) ^ (l15&7); bank-spread ~2-way
  const int aBase = l15 * 256 + (((wk * 4 + l4) ^ (l15 & 7)) * 16);

  // reduce-exchange swizzle constants (writer side)
  int nb16[2], hn[2];
#pragma unroll
  for (int nf = 0; nf < 2; nf++) {
    int n = wn * 32 + nf * 16 + l15;
    nb16[nf] = n * 32;
    hn[nf] = (n ^ (n >> 3)) & 7;
  }
  // reader side: thread owns cells (rows 4*rfr..4*rfr+3, unit ucell)
  const int ucell = tid & 15;
  const int rfr = tid >> 4;
  int ra16[4];
#pragma unroll
  for (int g2 = 0; g2 < 4; g2++) {
    int n = 4 * ucell + g2;
    ra16[g2] = n * 32 + (rfr ^ ((n ^ (n >> 3)) & 7));
  }
  char* lds = (char*)&Ab[0][0];

  f4 acc[8][2];

#define STAGE_H(C, BUF) do { \
    _Pragma("unroll") \
    for (int i = 0; i < 4; i++) \
      __builtin_amdgcn_global_load_lds( \
          (const __attribute__((address_space(1))) void*)(hsrcg + hoffc[i] + (C) * 16384), \
          (__attribute__((address_space(3))) void*)((char*)&Ab[BUF][0] + (w * 4 + i) * 1024), \
          16, 0, 0); \
  } while (0)

#define STAGE_X() do { \
    _Pragma("unroll") \
    for (int i = 0; i < 4; i++) \
      __builtin_amdgcn_global_load_lds( \
          (const __attribute__((address_space(1))) void*)(xslab + xoff[i]), \
          (__attribute__((address_space(3))) void*)((char*)&Ab[3][0] + (w * 4 + i) * 1024), \
          16, 0, 0); \
  } while (0)

#define COMPUTE(C, BUF) do { \
    const char* _b = (const char*)&Ab[BUF][0] + aBase; \
    half8 a0 = *(const half8*)(_b); \
    half8 a1 = *(const half8*)(_b + 4096); \
    half8 a2 = *(const half8*)(_b + 8192); \
    half8 a3 = *(const half8*)(_b + 12288); \
    half8 a4 = *(const half8*)(_b + 16384); \
    half8 a5 = *(const half8*)(_b + 20480); \
    half8 a6 = *(const half8*)(_b + 24576); \
    half8 a7 = *(const half8*)(_b + 28672); \
    acc[0][0] = __builtin_amdgcn_mfma_f32_16x16x32_f16(a0, bf[C][0], acc[0][0], 0, 0, 0); \
    acc[0][1] = __builtin_amdgcn_mfma_f32_16x16x32_f16(a0, bf[C][1], acc[0][1], 0, 0, 0); \
    acc[1][0] = __builtin_amdgcn_mfma_f32_16x16x32_f16(a1, bf[C][0], acc[1][0], 0, 0, 0); \
    acc[1][1] = __builtin_amdgcn_mfma_f32_16x16x32_f16(a1, bf[C][1], acc[1][1], 0, 0, 0); \
    acc[2][0] = __builtin_amdgcn_mfma_f32_16x16x32_f16(a2, bf[C][0], acc[2][0], 0, 0, 0); \
    acc[2][1] = __builtin_amdgcn_mfma_f32_16x16x32_f16(a2, bf[C][1], acc[2][1], 0, 0, 0); \
    acc[3][0] = __builtin_amdgcn_mfma_f32_16x16x32_f16(a3, bf[C][0], acc[3][0], 0, 0, 0); \
    acc[3][1] = __builtin_amdgcn_mfma_f32_16x16x32_f16(a3, bf[C][1], acc[3][1], 0, 0, 0); \
    acc[4][0] = __builtin_amdgcn_mfma_f32_16x16x32_f16(a4, bf[C][0], acc[4][0], 0, 0, 0); \
    acc[4][1] = __builtin_amdgcn_mfma_f32_16x16x32_f16(a4, bf[C][1], acc[4][1], 0, 0, 0); \
    acc[5][0] = __builtin_amdgcn_mfma_f32_16x16x32_f16(a5, bf[C][0], acc[5][0], 0, 0, 0); \
    acc[5][1] = __builtin_amdgcn_mfma_f32_16x16x32_f16(a5, bf[C][1], acc[5][1], 0, 0, 0); \
    acc[6][0] = __builtin_amdgcn_mfma_f32_16x16x32_f16(a6, bf[C][0], acc[6][0], 0, 0, 0); \
    acc[6][1] = __builtin_amdgcn_mfma_f32_16x16x32_f16(a6, bf[C][1], acc[6][1], 0, 0, 0); \
    acc[7][0] = __builtin_amdgcn_mfma_f32_16x16x32_f16(a7, bf[C][0], acc[7][0], 0, 0, 0); \
    acc[7][1] = __builtin_amdgcn_mfma_f32_16x16x32_f16(a7, bf[C][1], acc[7][1], 0, 0, 0); \
  } while (0)

  f4 creg = {0.f, 0.f, 0.f, 0.f};   // 4 cells (rows 4*rfr+j, unit ucell)

#pragma unroll 1
  for (int t = 0; t < kSteps; t++) {
    const unsigned short* hsrcg = ((t & 1) ? h1 : h0) + gblk * 131072;
    unsigned short* hdst = (t & 1) ? h0 : h1;
    const unsigned short* xslab = xT + (size_t)t * (512 * 128);

#pragma unroll
    for (int m = 0; m < 8; m++) {
      acc[m][0] = (f4){bseed0, bseed0, bseed0, bseed0};
      acc[m][1] = (f4){bseed1, bseed1, bseed1, bseed1};
    }

    STAGE_X();                   // flies during the group-barrier wait

    if (tid == 0) {              // all 64 blocks of this group finished step t-1?
      int target = 64 * t;
      int guard = 1 << 18;
      while (guard--) {
        int c;
        asm volatile("global_load_dword %0, %1, off sc0 sc1\n\ts_waitcnt vmcnt(0)"
                     : "=v"(c) : "v"(cntp) : "memory");
        if (c >= target) break;
        __builtin_amdgcn_s_sleep(2);
      }
      int f = __hip_atomic_load(cntp, __ATOMIC_ACQUIRE, __HIP_MEMORY_SCOPE_AGENT);
      asm volatile("" :: "v"(f));
    }
    __syncthreads();             // join; drains x staging (vmcnt 0)

    STAGE_H(0, 0); STAGE_H(1, 1);     // 8 in flight
    COMPUTE(8, 3);                    // x contribution (buf3 resident)
    STAGE_H(2, 2);                    // 12 in flight
    WAITBAR(8);  COMPUTE(0, 0);
    STAGE_H(3, 3);
    WAITBAR(8);  COMPUTE(1, 1);
    STAGE_H(4, 0);
    WAITBAR(8);  COMPUTE(2, 2);
    STAGE_H(5, 1);
    WAITBAR(8);  COMPUTE(3, 3);
    STAGE_H(6, 2);
    WAITBAR(8);  COMPUTE(4, 0);
    STAGE_H(7, 3);
    WAITBAR(8);  COMPUTE(5, 1);
    WAITBAR(4);  COMPUTE(6, 2);
    WAITBAR(0);  COMPUTE(7, 3);

    // ---- 4-way K reduction: all waves write acc, all threads read their cells ----
    asm volatile("s_waitcnt lgkmcnt(0)\n\ts_barrier" ::: "memory");  // staging reads done
#pragma unroll
    for (int m = 0; m < 8; m++)
#pragma unroll
      for (int nf = 0; nf < 2; nf++) {
        int rf = m * 4 + l4;
        *(f4*)(lds + (size_t)(wk * 2048 + nb16[nf] + (rf ^ hn[nf])) * 16) = acc[m][nf];
      }
    __syncthreads();
    {
      f4 gs[4];
#pragma unroll
      for (int g2 = 0; g2 < 4; g2++) {
        f4 v0 = *(const f4*)(lds + (size_t)ra16[g2] * 16);
        f4 v1 = *(const f4*)(lds + 32768 + (size_t)ra16[g2] * 16);
        f4 v2 = *(const f4*)(lds + 65536 + (size_t)ra16[g2] * 16);
        f4 v3 = *(const f4*)(lds + 98304 + (size_t)ra16[g2] * 16);
        gs[g2] = (v0 + v1) + (v2 + v3);
      }
      size_t hb = (size_t)((gblk * 64 + cblk) * 128 + rfr * 4) * 16 + ucell;
#pragma unroll
      for (int j = 0; j < 4; j++) {
        float ig = 1.f / (1.f + __expf(-gs[0][j]));
        float fg = 1.f / (1.f + __expf(-gs[1][j]));
        float gg = 2.f / (1.f + __expf(-2.f * gs[2][j])) - 1.f;
        float og = 1.f / (1.f + __expf(-gs[3][j]));
        float cn = fg * creg[j] + ig * gg;
        creg[j] = cn;
        float th = 2.f / (1.f + __expf(-2.f * cn)) - 1.f;
        hdst[hb + j * 16] = f2h(og * th);
      }
    }
    __syncthreads();             // drains h stores + reduce reads before next step
    if (tid == 0)
      __hip_atomic_fetch_add(cntp, 1, __ATOMIC_RELEASE, __HIP_MEMORY_SCOPE_AGENT);
  }
#undef STAGE_H
#undef STAGE_X
#undef COMPUTE
}

// ---------- FC: out = h_last @ W_fc^T + b_fc ----------
__global__ void fc_kernel(const char* __restrict__ ws, const float* __restrict__ Wfc,
                          const float* __restrict__ bfc, float* __restrict__ out) {
  const unsigned short* h = (const unsigned short*)(ws + OFF_H1);  // t=254 writes h1
  int o = threadIdx.x & 127;
  int b = blockIdx.x * 2 + (threadIdx.x >> 7);
  const float* wrow = Wfc + (size_t)o * 1024;
  float acc = bfc[o];
  int gb = b >> 7, rb = b & 127;
#pragma unroll 4
  for (int k = 0; k < 1024; k += 8) {
    ushort8 hv = *(const ushort8*)&h[((size_t)(gb * 64 + (k >> 4)) * 128 + rb) * 16 + (k & 15)];
    f4 w0 = *(const f4*)&wrow[k];
    f4 w1 = *(const f4*)&wrow[k + 4];
#pragma unroll
    for (int j = 0; j < 4; j++) acc += h2f(hv[j]) * w0[j];
#pragma unroll
    for (int j = 0; j < 4; j++) acc += h2f(hv[4 + j]) * w1[j];
  }
  out[(size_t)b * 128 + o] = acc;
}

extern "C" void kernel_launch(void* const* d_in, const int* in_sizes, int n_in,
                              void* d_out, int out_size, void* d_ws, size_t ws_size,
                              hipStream_t stream) {
  const float* x   = (const float*)d_in[0];
  const float* Wih = (const float*)d_in[1];
  const float* Whh = (const float*)d_in[2];
  const float* bih = (const float*)d_in[3];
  const float* bhh = (const float*)d_in[4];
  const float* Wfc = (const float*)d_in[5];
  const float* bfc = (const float*)d_in[6];
  char* ws = (char*)d_ws;

  hipMemsetAsync(ws + OFF_H0, 0, ((size_t)1 << 20) + 4096, stream);
  prep_wcat<<<2320, 256, 0, stream>>>(Wih, Whh, bih, bhh, ws);
  prep_xt<<<2048, 256, 0, stream>>>(x, ws);
  lstm_persist<<<256, 512, 0, stream>>>(ws);
  fc_kernel<<<256, 256, 0, stream>>>(ws, Wfc, bfc, (float*)d_out);
}

// Round 6
// 5160.476 us; speedup vs baseline: 1.9006x; 1.0401x over previous
//
#include <hip/hip_runtime.h>
#include <stdint.h>
#include <stddef.h>

typedef __attribute__((ext_vector_type(8))) _Float16 half8;
typedef __attribute__((ext_vector_type(8))) unsigned short ushort8;
typedef __attribute__((ext_vector_type(4))) float f4;

namespace {
constexpr int kSteps = 255;   // reference iterates t = 0 .. T-2
constexpr int KTOT = 1152;    // 1024 (h) + 128 (x)

// workspace layout (bytes); total ~45 MB
// h layout: [group(4)][ub(64)][row(128)][u(16)] fp16 -> block-contiguous 4KB slices
constexpr size_t OFF_H0   = 0;                                   // 1 MB  h ping
constexpr size_t OFF_CNT  = (size_t)1 << 20;                     // 4 KB  barrier counters
constexpr size_t OFF_H1   = ((size_t)1 << 20) + 4096;            // 1 MB  h pong
constexpr size_t OFF_BSUM = OFF_H1 + ((size_t)1 << 20);          // 16 KB b_ih+b_hh (fp32)
constexpr size_t OFF_WCAT = OFF_BSUM + 16384;                    // 9.4 MB fp16 [4096][1152]
constexpr size_t OFF_XT   = OFF_WCAT + (size_t)4096 * KTOT * 2;  // 33.4 MB fp16 [255][512][128]
}

__device__ __forceinline__ unsigned short f2h(float f) {
  _Float16 h = (_Float16)f;
  return __builtin_bit_cast(unsigned short, h);
}
__device__ __forceinline__ float h2f(unsigned short s) {
  return (float)__builtin_bit_cast(_Float16, s);
}

// ---------- prep 1: Wcat fp16 + bsum ----------
__global__ void prep_wcat(const float* __restrict__ Wih, const float* __restrict__ Whh,
                          const float* __restrict__ bih, const float* __restrict__ bhh,
                          char* __restrict__ ws) {
  if (blockIdx.x < 2304) {
    unsigned gid = blockIdx.x * 256 + threadIdx.x;
    unsigned row = gid / 144, cc = gid % 144;
    const float* src = (cc < 128) ? (Whh + (size_t)row * 1024 + (size_t)cc * 8)
                                  : (Wih + (size_t)row * 128 + (size_t)(cc - 128) * 8);
    ushort8 o;
#pragma unroll
    for (int j = 0; j < 8; j++) o[j] = f2h(src[j]);
    *(ushort8*)((unsigned short*)(ws + OFF_WCAT) + (size_t)row * KTOT + cc * 8) = o;
  } else {
    int i = (blockIdx.x - 2304) * 256 + threadIdx.x;
    ((float*)(ws + OFF_BSUM))[i] = bih[i] + bhh[i];
  }
}

// ---------- prep 2: xT[t][b][i] = fp16(x[b][i][t]) ----------
__global__ void prep_xt(const float* __restrict__ x, char* __restrict__ ws) {
  unsigned short* xT = (unsigned short*)(ws + OFF_XT);
  __shared__ unsigned short tile[128][72];
  const int b = blockIdx.x >> 2;
  const int t0 = (blockIdx.x & 3) * 64;
  const int wv = threadIdx.x >> 6, tl = threadIdx.x & 63;
  if (t0 + tl < 255) {
#pragma unroll
    for (int ii = 0; ii < 32; ii++) {
      int i = wv + ii * 4;
      tile[i][tl] = f2h(x[((size_t)b * 128 + i) * 256 + t0 + tl]);
    }
  }
  __syncthreads();
  const int tl2 = threadIdx.x >> 4, ic = threadIdx.x & 15;
#pragma unroll
  for (int pp = 0; pp < 4; pp++) {
    int tloc = pp * 16 + tl2;
    int t = t0 + tloc;
    if (t < 255) {
      ushort8 v;
#pragma unroll
      for (int j = 0; j < 8; j++) v[j] = tile[ic * 8 + j][tloc];
      *(ushort8*)&xT[((size_t)t * 512 + b) * 128 + ic * 8] = v;
    }
  }
}

// counted-vmcnt + barrier (T3/T4)
#define WAITBAR(N) do { \
    asm volatile("s_waitcnt vmcnt(" #N ") lgkmcnt(0)\n\ts_barrier" ::: "memory"); \
    __builtin_amdgcn_sched_barrier(0); \
  } while (0)

// ---------- persistent LSTM kernel ----------
// grid 256 = 4 groups (128 rows) x 64 unit-blocks (16 units). 8 waves = 4K x 2N.
// Wave tile: M=128, N=32, K=288 (k-slice kk==wk mod 4 within each 128-col chunk).
// Weights: bf[9][2] = 72 VGPR. acc[8][2] f4 = 64 AGPR. Zero scratch by construction.
__global__ __launch_bounds__(512, 1) void lstm_persist(char* __restrict__ ws) {
  const unsigned short* __restrict__ wcat = (const unsigned short*)(ws + OFF_WCAT);
  const float* __restrict__ bsum = (const float*)(ws + OFF_BSUM);
  const unsigned short* __restrict__ xT = (const unsigned short*)(ws + OFF_XT);
  unsigned short* h0 = (unsigned short*)(ws + OFF_H0);
  unsigned short* h1 = (unsigned short*)(ws + OFF_H1);

  __shared__ __align__(16) unsigned short Ab[4][16384];   // 4 x 32KB chunk bufs / reduce scratch

  const int tid = threadIdx.x;
  const int lane = tid & 63;
  const int w = tid >> 6;
  const int wk = w & 3;           // K group (k-slice parity mod 4)
  const int wn = w >> 2;          // N half
  const int l15 = lane & 15, l4 = lane >> 4;
  const int gblk = blockIdx.x >> 6;
  const int cblk = blockIdx.x & 63;
  const int B0 = gblk * 128;
  const int U0 = cblk * 16;
  int* cntp = (int*)(ws + OFF_CNT) + gblk * 16;

  // ---- weight fragments -> registers (col n = wn*32+nf*16+l15 -> unit n>>2, gate n&3) ----
  half8 bf[9][2];
  float bs[2];
#pragma unroll
  for (int nf = 0; nf < 2; nf++) {
    int u = wn * 8 + nf * 4 + (l15 >> 2);
    int R = (l15 & 3) * 1024 + U0 + u;          // PyTorch gate order i,f,g,o
    bs[nf] = bsum[R];
#pragma unroll
    for (int c = 0; c < 9; c++)
      bf[c][nf] = *(const half8*)&wcat[(size_t)R * KTOT + c * 128 + wk * 32 + l4 * 8];
  }
  const float bseed0 = (wk == 0) ? bs[0] : 0.f;
  const float bseed1 = (wk == 0) ? bs[1] : 0.f;

  // ---- staging: 32 slots of 1KB per 32KB chunk; slot s = w*4+i (wave-uniform LDS base) ----
  // LDS (row, c16) holds G(row, c16 ^ (row&7)); source pre-inverse-swizzled (rule #21).
  int hoffc[4], xoff[4];
#pragma unroll
  for (int i = 0; i < 4; i++) {
    int s = w * 4 + i;
    int row = s * 4 + (lane >> 4);
    int cg = (lane & 15) ^ (row & 7);
    hoffc[i] = (cg >> 1) * 2048 + row * 16 + (cg & 1) * 8;   // + c*16384, + group base
    xoff[i] = (B0 + row) * 128 + cg * 8;
  }
  // A ds_read: row = m*16+l15, c16 = (wk*4+l4) ^ (l15&7); bank-spread ~uniform
  const int aBase = l15 * 256 + (((wk * 4 + l4) ^ (l15 & 7)) * 16);

  // reduce-exchange swizzle constants (writer side)
  int nb16[2], hn[2];
#pragma unroll
  for (int nf = 0; nf < 2; nf++) {
    int n = wn * 32 + nf * 16 + l15;
    nb16[nf] = n * 32;
    hn[nf] = (n ^ (n >> 3)) & 7;
  }
  // reader side: thread owns cells (rows 4*rfr..4*rfr+3, unit ucell)
  const int ucell = tid & 15;
  const int rfr = tid >> 4;
  int ra16[4];
#pragma unroll
  for (int g2 = 0; g2 < 4; g2++) {
    int n = 4 * ucell + g2;
    ra16[g2] = n * 32 + (rfr ^ ((n ^ (n >> 3)) & 7));
  }
  char* lds = (char*)&Ab[0][0];

  f4 acc[8][2];

#define STAGE_H(C, BUF) do { \
    _Pragma("unroll") \
    for (int i = 0; i < 4; i++) \
      __builtin_amdgcn_global_load_lds( \
          (const __attribute__((address_space(1))) void*)(hsrcg + hoffc[i] + (C) * 16384), \
          (__attribute__((address_space(3))) void*)((char*)&Ab[BUF][0] + (w * 4 + i) * 1024), \
          16, 0, 0); \
  } while (0)

#define STAGE_X() do { \
    _Pragma("unroll") \
    for (int i = 0; i < 4; i++) \
      __builtin_amdgcn_global_load_lds( \
          (const __attribute__((address_space(1))) void*)(xslab + xoff[i]), \
          (__attribute__((address_space(3))) void*)((char*)&Ab[3][0] + (w * 4 + i) * 1024), \
          16, 0, 0); \
  } while (0)

#define COMPUTE(C, BUF) do { \
    const char* _b = (const char*)&Ab[BUF][0] + aBase; \
    half8 a0 = *(const half8*)(_b); \
    half8 a1 = *(const half8*)(_b + 4096); \
    half8 a2 = *(const half8*)(_b + 8192); \
    half8 a3 = *(const half8*)(_b + 12288); \
    half8 a4 = *(const half8*)(_b + 16384); \
    half8 a5 = *(const half8*)(_b + 20480); \
    half8 a6 = *(const half8*)(_b + 24576); \
    half8 a7 = *(const half8*)(_b + 28672); \
    acc[0][0] = __builtin_amdgcn_mfma_f32_16x16x32_f16(a0, bf[C][0], acc[0][0], 0, 0, 0); \
    acc[0][1] = __builtin_amdgcn_mfma_f32_16x16x32_f16(a0, bf[C][1], acc[0][1], 0, 0, 0); \
    acc[1][0] = __builtin_amdgcn_mfma_f32_16x16x32_f16(a1, bf[C][0], acc[1][0], 0, 0, 0); \
    acc[1][1] = __builtin_amdgcn_mfma_f32_16x16x32_f16(a1, bf[C][1], acc[1][1], 0, 0, 0); \
    acc[2][0] = __builtin_amdgcn_mfma_f32_16x16x32_f16(a2, bf[C][0], acc[2][0], 0, 0, 0); \
    acc[2][1] = __builtin_amdgcn_mfma_f32_16x16x32_f16(a2, bf[C][1], acc[2][1], 0, 0, 0); \
    acc[3][0] = __builtin_amdgcn_mfma_f32_16x16x32_f16(a3, bf[C][0], acc[3][0], 0, 0, 0); \
    acc[3][1] = __builtin_amdgcn_mfma_f32_16x16x32_f16(a3, bf[C][1], acc[3][1], 0, 0, 0); \
    acc[4][0] = __builtin_amdgcn_mfma_f32_16x16x32_f16(a4, bf[C][0], acc[4][0], 0, 0, 0); \
    acc[4][1] = __builtin_amdgcn_mfma_f32_16x16x32_f16(a4, bf[C][1], acc[4][1], 0, 0, 0); \
    acc[5][0] = __builtin_amdgcn_mfma_f32_16x16x32_f16(a5, bf[C][0], acc[5][0], 0, 0, 0); \
    acc[5][1] = __builtin_amdgcn_mfma_f32_16x16x32_f16(a5, bf[C][1], acc[5][1], 0, 0, 0); \
    acc[6][0] = __builtin_amdgcn_mfma_f32_16x16x32_f16(a6, bf[C][0], acc[6][0], 0, 0, 0); \
    acc[6][1] = __builtin_amdgcn_mfma_f32_16x16x32_f16(a6, bf[C][1], acc[6][1], 0, 0, 0); \
    acc[7][0] = __builtin_amdgcn_mfma_f32_16x16x32_f16(a7, bf[C][0], acc[7][0], 0, 0, 0); \
    acc[7][1] = __builtin_amdgcn_mfma_f32_16x16x32_f16(a7, bf[C][1], acc[7][1], 0, 0, 0); \
  } while (0)

  f4 creg = {0.f, 0.f, 0.f, 0.f};   // 4 cells (rows 4*rfr+j, unit ucell)

#pragma unroll 1
  for (int t = 0; t < kSteps; t++) {
    const unsigned short* hsrcg = ((t & 1) ? h1 : h0) + gblk * 131072;
    unsigned short* hdst = (t & 1) ? h0 : h1;
    const unsigned short* xslab = xT + (size_t)t * (512 * 128);

#pragma unroll
    for (int m = 0; m < 8; m++) {
      acc[m][0] = (f4){bseed0, bseed0, bseed0, bseed0};
      acc[m][1] = (f4){bseed1, bseed1, bseed1, bseed1};
    }

    STAGE_X();                   // flies during the group-barrier wait

    if (tid == 0) {
      // EARLY acquire/inv: clear stale h_P lines BEFORE waiting. Post-arrival
      // fetches then populate L2 and STAY valid -> co-XCD blocks share them.
      // Freshness: writers' release-wbl2 makes their lines clean-and-current;
      // nothing re-caches buffer P between this inv and our post-spin reads.
      int f0 = __hip_atomic_load(cntp, __ATOMIC_ACQUIRE, __HIP_MEMORY_SCOPE_AGENT);
      asm volatile("" :: "v"(f0));
      int target = 64 * t;
      int guard = 1 << 18;
      while (guard--) {           // relaxed LLC-bypass polling: no L2 thrash
        int c;
        asm volatile("global_load_dword %0, %1, off sc0 sc1\n\ts_waitcnt vmcnt(0)"
                     : "=v"(c) : "v"(cntp) : "memory");
        if (c >= target) break;
        __builtin_amdgcn_s_sleep(2);
      }
    }
    __syncthreads();             // join; drains x staging (vmcnt 0)

    STAGE_H(0, 0); STAGE_H(1, 1);     // 8 in flight
    COMPUTE(8, 3);                    // x contribution (buf3 resident)
    STAGE_H(2, 2);                    // 12 in flight
    WAITBAR(8);  COMPUTE(0, 0);
    STAGE_H(3, 3);
    WAITBAR(8);  COMPUTE(1, 1);
    STAGE_H(4, 0);
    WAITBAR(8);  COMPUTE(2, 2);
    STAGE_H(5, 1);
    WAITBAR(8);  COMPUTE(3, 3);
    STAGE_H(6, 2);
    WAITBAR(8);  COMPUTE(4, 0);
    STAGE_H(7, 3);
    WAITBAR(8);  COMPUTE(5, 1);
    WAITBAR(4);  COMPUTE(6, 2);
    WAITBAR(0);  COMPUTE(7, 3);

    // ---- 4-way K reduction: all waves write acc, all threads read their cells ----
    asm volatile("s_waitcnt lgkmcnt(0)\n\ts_barrier" ::: "memory");  // staging reads done
#pragma unroll
    for (int m = 0; m < 8; m++)
#pragma unroll
      for (int nf = 0; nf < 2; nf++) {
        int rf = m * 4 + l4;
        *(f4*)(lds + (size_t)(wk * 2048 + nb16[nf] + (rf ^ hn[nf])) * 16) = acc[m][nf];
      }
    __syncthreads();
    {
      f4 gs[4];
#pragma unroll
      for (int g2 = 0; g2 < 4; g2++) {
        f4 v0 = *(const f4*)(lds + (size_t)ra16[g2] * 16);
        f4 v1 = *(const f4*)(lds + 32768 + (size_t)ra16[g2] * 16);
        f4 v2 = *(const f4*)(lds + 65536 + (size_t)ra16[g2] * 16);
        f4 v3 = *(const f4*)(lds + 98304 + (size_t)ra16[g2] * 16);
        gs[g2] = (v0 + v1) + (v2 + v3);
      }
      size_t hb = (size_t)((gblk * 64 + cblk) * 128 + rfr * 4) * 16 + ucell;
#pragma unroll
      for (int j = 0; j < 4; j++) {
        float ig = 1.f / (1.f + __expf(-gs[0][j]));
        float fg = 1.f / (1.f + __expf(-gs[1][j]));
        float gg = 2.f / (1.f + __expf(-2.f * gs[2][j])) - 1.f;
        float og = 1.f / (1.f + __expf(-gs[3][j]));
        float cn = fg * creg[j] + ig * gg;
        creg[j] = cn;
        float th = 2.f / (1.f + __expf(-2.f * cn)) - 1.f;
        hdst[hb + j * 16] = f2h(og * th);
      }
    }
    __syncthreads();             // drains h stores + reduce reads before next step
    if (tid == 0)
      __hip_atomic_fetch_add(cntp, 1, __ATOMIC_RELEASE, __HIP_MEMORY_SCOPE_AGENT);
  }
#undef STAGE_H
#undef STAGE_X
#undef COMPUTE
}

// ---------- FC: out = h_last @ W_fc^T + b_fc ----------
__global__ void fc_kernel(const char* __restrict__ ws, const float* __restrict__ Wfc,
                          const float* __restrict__ bfc, float* __restrict__ out) {
  const unsigned short* h = (const unsigned short*)(ws + OFF_H1);  // t=254 writes h1
  int o = threadIdx.x & 127;
  int b = blockIdx.x * 2 + (threadIdx.x >> 7);
  const float* wrow = Wfc + (size_t)o * 1024;
  float acc = bfc[o];
  int gb = b >> 7, rb = b & 127;
#pragma unroll 4
  for (int k = 0; k < 1024; k += 8) {
    ushort8 hv = *(const ushort8*)&h[((size_t)(gb * 64 + (k >> 4)) * 128 + rb) * 16 + (k & 15)];
    f4 w0 = *(const f4*)&wrow[k];
    f4 w1 = *(const f4*)&wrow[k + 4];
#pragma unroll
    for (int j = 0; j < 4; j++) acc += h2f(hv[j]) * w0[j];
#pragma unroll
    for (int j = 0; j < 4; j++) acc += h2f(hv[4 + j]) * w1[j];
  }
  out[(size_t)b * 128 + o] = acc;
}

extern "C" void kernel_launch(void* const* d_in, const int* in_sizes, int n_in,
                              void* d_out, int out_size, void* d_ws, size_t ws_size,
                              hipStream_t stream) {
  const float* x   = (const float*)d_in[0];
  const float* Wih = (const float*)d_in[1];
  const float* Whh = (const float*)d_in[2];
  const float* bih = (const float*)d_in[3];
  const float* bhh = (const float*)d_in[4];
  const float* Wfc = (const float*)d_in[5];
  const float* bfc = (const float*)d_in[6];
  char* ws = (char*)d_ws;

  hipMemsetAsync(ws + OFF_H0, 0, ((size_t)1 << 20) + 4096, stream);
  prep_wcat<<<2320, 256, 0, stream>>>(Wih, Whh, bih, bhh, ws);
  prep_xt<<<2048, 256, 0, stream>>>(x, ws);
  lstm_persist<<<256, 512, 0, stream>>>(ws);
  fc_kernel<<<256, 256, 0, stream>>>(ws, Wfc, bfc, (float*)d_out);
}

// Round 8
// 2563.010 us; speedup vs baseline: 3.8267x; 2.0134x over previous
//
#include <hip/hip_runtime.h>
#include <stdint.h>
#include <stddef.h>

typedef __attribute__((ext_vector_type(8))) _Float16 half8;
typedef __attribute__((ext_vector_type(8))) unsigned short ushort8;
typedef __attribute__((ext_vector_type(4))) float f4;

namespace {
constexpr int kSteps = 255;   // reference iterates t = 0 .. T-2
constexpr int KTOT = 1152;    // 1024 (h) + 128 (x)

// workspace layout (bytes); total ~45 MB
// h layout: [group(4)][ub(64)][row(128)][u(16)] fp16 -> block-contiguous 4KB slices
constexpr size_t OFF_H0   = 0;                                   // 1 MB  h ping
constexpr size_t OFF_CNT  = (size_t)1 << 20;                     // 4 KB  barrier counters
constexpr size_t OFF_H1   = ((size_t)1 << 20) + 4096;            // 1 MB  h pong
constexpr size_t OFF_BSUM = OFF_H1 + ((size_t)1 << 20);          // 16 KB b_ih+b_hh (fp32)
constexpr size_t OFF_WCAT = OFF_BSUM + 16384;                    // 9.4 MB fp16 [4096][1152]
constexpr size_t OFF_XT   = OFF_WCAT + (size_t)4096 * KTOT * 2;  // 33.4 MB fp16 [255][512][128]
}

__device__ __forceinline__ unsigned short f2h(float f) {
  _Float16 h = (_Float16)f;
  return __builtin_bit_cast(unsigned short, h);
}
__device__ __forceinline__ float h2f(unsigned short s) {
  return (float)__builtin_bit_cast(_Float16, s);
}

// ---------- prep 1: Wcat fp16 + bsum ----------
__global__ void prep_wcat(const float* __restrict__ Wih, const float* __restrict__ Whh,
                          const float* __restrict__ bih, const float* __restrict__ bhh,
                          char* __restrict__ ws) {
  if (blockIdx.x < 2304) {
    unsigned gid = blockIdx.x * 256 + threadIdx.x;
    unsigned row = gid / 144, cc = gid % 144;
    const float* src = (cc < 128) ? (Whh + (size_t)row * 1024 + (size_t)cc * 8)
                                  : (Wih + (size_t)row * 128 + (size_t)(cc - 128) * 8);
    ushort8 o;
#pragma unroll
    for (int j = 0; j < 8; j++) o[j] = f2h(src[j]);
    *(ushort8*)((unsigned short*)(ws + OFF_WCAT) + (size_t)row * KTOT + cc * 8) = o;
  } else {
    int i = (blockIdx.x - 2304) * 256 + threadIdx.x;
    ((float*)(ws + OFF_BSUM))[i] = bih[i] + bhh[i];
  }
}

// ---------- prep 2: xT[t][b][i] = fp16(x[b][i][t]) ----------
__global__ void prep_xt(const float* __restrict__ x, char* __restrict__ ws) {
  unsigned short* xT = (unsigned short*)(ws + OFF_XT);
  __shared__ unsigned short tile[128][72];
  const int b = blockIdx.x >> 2;
  const int t0 = (blockIdx.x & 3) * 64;
  const int wv = threadIdx.x >> 6, tl = threadIdx.x & 63;
  if (t0 + tl < 255) {
#pragma unroll
    for (int ii = 0; ii < 32; ii++) {
      int i = wv + ii * 4;
      tile[i][tl] = f2h(x[((size_t)b * 128 + i) * 256 + t0 + tl]);
    }
  }
  __syncthreads();
  const int tl2 = threadIdx.x >> 4, ic = threadIdx.x & 15;
#pragma unroll
  for (int pp = 0; pp < 4; pp++) {
    int tloc = pp * 16 + tl2;
    int t = t0 + tloc;
    if (t < 255) {
      ushort8 v;
#pragma unroll
      for (int j = 0; j < 8; j++) v[j] = tile[ic * 8 + j][tloc];
      *(ushort8*)&xT[((size_t)t * 512 + b) * 128 + ic * 8] = v;
    }
  }
}

// counted-vmcnt + barrier (T3/T4)
#define WAITBAR(N) do { \
    asm volatile("s_waitcnt vmcnt(" #N ") lgkmcnt(0)\n\ts_barrier" ::: "memory"); \
    __builtin_amdgcn_sched_barrier(0); \
  } while (0)

// ---------- persistent LSTM kernel ----------
// grid 256 = 4 groups (128 rows) x 64 unit-blocks (16 units). 8 waves = 4K x 2N.
// Wave tile: M=128, N=32, K=288 (k-slice kk==wk mod 4 within each 128-col chunk).
// Coherence: h stores write-through (sc0 sc1) -> LLC; no dirty h in any L2 ->
// release = RELAXED atomic (no buffer_wbl2 L2-walk); readers: one inv/step.
// Staging schedule: r6's proven 2-deep (every buffer overwrite is one full
// WAITBAR (lgkmcnt0+barrier) after its last reader -- no LDS WAR race).
__global__ __launch_bounds__(512, 1) void lstm_persist(char* __restrict__ ws) {
  const unsigned short* __restrict__ wcat = (const unsigned short*)(ws + OFF_WCAT);
  const float* __restrict__ bsum = (const float*)(ws + OFF_BSUM);
  const unsigned short* __restrict__ xT = (const unsigned short*)(ws + OFF_XT);
  unsigned short* h0 = (unsigned short*)(ws + OFF_H0);
  unsigned short* h1 = (unsigned short*)(ws + OFF_H1);

  __shared__ __align__(16) unsigned short Ab[4][16384];   // 4 x 32KB chunk bufs / reduce scratch

  const int tid = threadIdx.x;
  const int lane = tid & 63;
  const int w = tid >> 6;
  const int wk = w & 3;           // K group (k-slice parity mod 4)
  const int wn = w >> 2;          // N half
  const int l15 = lane & 15, l4 = lane >> 4;
  const int gblk = blockIdx.x >> 6;
  const int cblk = blockIdx.x & 63;
  const int B0 = gblk * 128;
  const int U0 = cblk * 16;
  int* cntp = (int*)(ws + OFF_CNT) + gblk * 16;

  // ---- weight fragments -> registers (col n = wn*32+nf*16+l15 -> unit n>>2, gate n&3) ----
  half8 bf[9][2];
  float bs[2];
#pragma unroll
  for (int nf = 0; nf < 2; nf++) {
    int u = wn * 8 + nf * 4 + (l15 >> 2);
    int R = (l15 & 3) * 1024 + U0 + u;          // PyTorch gate order i,f,g,o
    bs[nf] = bsum[R];
#pragma unroll
    for (int c = 0; c < 9; c++)
      bf[c][nf] = *(const half8*)&wcat[(size_t)R * KTOT + c * 128 + wk * 32 + l4 * 8];
  }
  const float bseed0 = (wk == 0) ? bs[0] : 0.f;
  const float bseed1 = (wk == 0) ? bs[1] : 0.f;

  // ---- staging: 32 slots of 1KB per 32KB chunk; slot s = w*4+i (wave-uniform LDS base) ----
  // LDS (row, c16) holds G(row, c16 ^ (row&7)); source pre-inverse-swizzled (rule #21).
  int hoffc[4], xoff[4];
#pragma unroll
  for (int i = 0; i < 4; i++) {
    int s = w * 4 + i;
    int row = s * 4 + (lane >> 4);
    int cg = (lane & 15) ^ (row & 7);
    hoffc[i] = (cg >> 1) * 2048 + row * 16 + (cg & 1) * 8;   // + c*16384, + group base
    xoff[i] = (B0 + row) * 128 + cg * 8;
  }
  // A ds_read: row = m*16+l15, c16 = (wk*4+l4) ^ (l15&7); bank-spread ~uniform
  const int aBase = l15 * 256 + (((wk * 4 + l4) ^ (l15 & 7)) * 16);

  // reduce-exchange swizzle constants (writer side)
  int nb16[2], hn[2];
#pragma unroll
  for (int nf = 0; nf < 2; nf++) {
    int n = wn * 32 + nf * 16 + l15;
    nb16[nf] = n * 32;
    hn[nf] = (n ^ (n >> 3)) & 7;
  }
  // reader side: thread owns cells (rows 4*rfr..4*rfr+3, unit ucell)
  const int ucell = tid & 15;
  const int rfr = tid >> 4;
  int ra16[4];
#pragma unroll
  for (int g2 = 0; g2 < 4; g2++) {
    int n = 4 * ucell + g2;
    ra16[g2] = n * 32 + (rfr ^ ((n ^ (n >> 3)) & 7));
  }
  char* lds = (char*)&Ab[0][0];

  f4 acc[8][2];

#define STAGE_H(C, BUF) do { \
    _Pragma("unroll") \
    for (int i = 0; i < 4; i++) \
      __builtin_amdgcn_global_load_lds( \
          (const __attribute__((address_space(1))) void*)(hsrcg + hoffc[i] + (C) * 16384), \
          (__attribute__((address_space(3))) void*)((char*)&Ab[BUF][0] + (w * 4 + i) * 1024), \
          16, 0, 0); \
  } while (0)

#define STAGE_X() do { \
    _Pragma("unroll") \
    for (int i = 0; i < 4; i++) \
      __builtin_amdgcn_global_load_lds( \
          (const __attribute__((address_space(1))) void*)(xslab + xoff[i]), \
          (__attribute__((address_space(3))) void*)((char*)&Ab[3][0] + (w * 4 + i) * 1024), \
          16, 0, 0); \
  } while (0)

#define COMPUTE(C, BUF) do { \
    const char* _b = (const char*)&Ab[BUF][0] + aBase; \
    half8 a0 = *(const half8*)(_b); \
    half8 a1 = *(const half8*)(_b + 4096); \
    half8 a2 = *(const half8*)(_b + 8192); \
    half8 a3 = *(const half8*)(_b + 12288); \
    half8 a4 = *(const half8*)(_b + 16384); \
    half8 a5 = *(const half8*)(_b + 20480); \
    half8 a6 = *(const half8*)(_b + 24576); \
    half8 a7 = *(const half8*)(_b + 28672); \
    acc[0][0] = __builtin_amdgcn_mfma_f32_16x16x32_f16(a0, bf[C][0], acc[0][0], 0, 0, 0); \
    acc[0][1] = __builtin_amdgcn_mfma_f32_16x16x32_f16(a0, bf[C][1], acc[0][1], 0, 0, 0); \
    acc[1][0] = __builtin_amdgcn_mfma_f32_16x16x32_f16(a1, bf[C][0], acc[1][0], 0, 0, 0); \
    acc[1][1] = __builtin_amdgcn_mfma_f32_16x16x32_f16(a1, bf[C][1], acc[1][1], 0, 0, 0); \
    acc[2][0] = __builtin_amdgcn_mfma_f32_16x16x32_f16(a2, bf[C][0], acc[2][0], 0, 0, 0); \
    acc[2][1] = __builtin_amdgcn_mfma_f32_16x16x32_f16(a2, bf[C][1], acc[2][1], 0, 0, 0); \
    acc[3][0] = __builtin_amdgcn_mfma_f32_16x16x32_f16(a3, bf[C][0], acc[3][0], 0, 0, 0); \
    acc[3][1] = __builtin_amdgcn_mfma_f32_16x16x32_f16(a3, bf[C][1], acc[3][1], 0, 0, 0); \
    acc[4][0] = __builtin_amdgcn_mfma_f32_16x16x32_f16(a4, bf[C][0], acc[4][0], 0, 0, 0); \
    acc[4][1] = __builtin_amdgcn_mfma_f32_16x16x32_f16(a4, bf[C][1], acc[4][1], 0, 0, 0); \
    acc[5][0] = __builtin_amdgcn_mfma_f32_16x16x32_f16(a5, bf[C][0], acc[5][0], 0, 0, 0); \
    acc[5][1] = __builtin_amdgcn_mfma_f32_16x16x32_f16(a5, bf[C][1], acc[5][1], 0, 0, 0); \
    acc[6][0] = __builtin_amdgcn_mfma_f32_16x16x32_f16(a6, bf[C][0], acc[6][0], 0, 0, 0); \
    acc[6][1] = __builtin_amdgcn_mfma_f32_16x16x32_f16(a6, bf[C][1], acc[6][1], 0, 0, 0); \
    acc[7][0] = __builtin_amdgcn_mfma_f32_16x16x32_f16(a7, bf[C][0], acc[7][0], 0, 0, 0); \
    acc[7][1] = __builtin_amdgcn_mfma_f32_16x16x32_f16(a7, bf[C][1], acc[7][1], 0, 0, 0); \
  } while (0)

  f4 creg = {0.f, 0.f, 0.f, 0.f};   // 4 cells (rows 4*rfr+j, unit ucell)

#pragma unroll 1
  for (int t = 0; t < kSteps; t++) {
    const unsigned short* hsrcg = ((t & 1) ? h1 : h0) + gblk * 131072;
    unsigned short* hdst = (t & 1) ? h0 : h1;
    const unsigned short* xslab = xT + (size_t)t * (512 * 128);

#pragma unroll
    for (int m = 0; m < 8; m++) {
      acc[m][0] = (f4){bseed0, bseed0, bseed0, bseed0};
      acc[m][1] = (f4){bseed1, bseed1, bseed1, bseed1};
    }

    STAGE_X();                   // flies during the group-barrier wait

    if (tid == 0) {
      // EARLY acquire/inv (cheap tag-clear; no writebacks exist since h is
      // write-through). Fresh h enters this XCD's L2 from LLC and is shared.
      int f0 = __hip_atomic_load(cntp, __ATOMIC_ACQUIRE, __HIP_MEMORY_SCOPE_AGENT);
      asm volatile("" :: "v"(f0));
      int target = 64 * t;
      int guard = 1 << 18;
      while (guard--) {           // relaxed LLC-bypass polling: no L2 thrash
        int c;
        asm volatile("global_load_dword %0, %1, off sc0 sc1\n\ts_waitcnt vmcnt(0)"
                     : "=v"(c) : "v"(cntp) : "memory");
        if (c >= target) break;
        __builtin_amdgcn_s_sleep(2);
      }
    }
    __syncthreads();             // join; drains x staging (vmcnt 0)

    // r6's proven 2-deep schedule (8 outstanding; overwrite >= 1 WAITBAR after last read)
    STAGE_H(0, 0); STAGE_H(1, 1);
    COMPUTE(8, 3);                    // x contribution (buf3 resident)
    STAGE_H(2, 2);
    WAITBAR(8);  COMPUTE(0, 0);
    STAGE_H(3, 3);
    WAITBAR(8);  COMPUTE(1, 1);
    STAGE_H(4, 0);
    WAITBAR(8);  COMPUTE(2, 2);
    STAGE_H(5, 1);
    WAITBAR(8);  COMPUTE(3, 3);
    STAGE_H(6, 2);
    WAITBAR(8);  COMPUTE(4, 0);
    STAGE_H(7, 3);
    WAITBAR(8);  COMPUTE(5, 1);
    WAITBAR(4);  COMPUTE(6, 2);
    WAITBAR(0);  COMPUTE(7, 3);

    // ---- 4-way K reduction: all waves write acc, all threads read their cells ----
    asm volatile("s_waitcnt lgkmcnt(0)\n\ts_barrier" ::: "memory");  // staging reads done
#pragma unroll
    for (int m = 0; m < 8; m++)
#pragma unroll
      for (int nf = 0; nf < 2; nf++) {
        int rf = m * 4 + l4;
        *(f4*)(lds + (size_t)(wk * 2048 + nb16[nf] + (rf ^ hn[nf])) * 16) = acc[m][nf];
      }
    __syncthreads();
    {
      f4 gs[4];
#pragma unroll
      for (int g2 = 0; g2 < 4; g2++) {
        f4 v0 = *(const f4*)(lds + (size_t)ra16[g2] * 16);
        f4 v1 = *(const f4*)(lds + 32768 + (size_t)ra16[g2] * 16);
        f4 v2 = *(const f4*)(lds + 65536 + (size_t)ra16[g2] * 16);
        f4 v3 = *(const f4*)(lds + 98304 + (size_t)ra16[g2] * 16);
        gs[g2] = (v0 + v1) + (v2 + v3);
      }
      size_t hb = (size_t)((gblk * 64 + cblk) * 128 + rfr * 4) * 16 + ucell;
#pragma unroll
      for (int j = 0; j < 4; j++) {
        float ig = 1.f / (1.f + __expf(-gs[0][j]));
        float fg = 1.f / (1.f + __expf(-gs[1][j]));
        float gg = 2.f / (1.f + __expf(-2.f * gs[2][j])) - 1.f;
        float og = 1.f / (1.f + __expf(-gs[3][j]));
        float cn = fg * creg[j] + ig * gg;
        creg[j] = cn;
        float th = 2.f / (1.f + __expf(-2.f * cn)) - 1.f;
        // write-through to LLC: coherent across XCDs, leaves no dirty L2 line
        unsigned short* hp = hdst + hb + (size_t)j * 16;
        unsigned hv = f2h(og * th);
        asm volatile("global_store_short %0, %1, off sc0 sc1"
                     :: "v"(hp), "v"(hv) : "memory");
      }
    }
    __syncthreads();             // drains h stores (vmcnt 0 -> ack'd at LLC) before arrival
    if (tid == 0)                // RELAXED: no buffer_wbl2 (nothing dirty to flush)
      __hip_atomic_fetch_add(cntp, 1, __ATOMIC_RELAXED, __HIP_MEMORY_SCOPE_AGENT);
  }
#undef STAGE_H
#undef STAGE_X
#undef COMPUTE
}

// ---------- FC: out = h_last @ W_fc^T + b_fc ----------
__global__ void fc_kernel(const char* __restrict__ ws, const float* __restrict__ Wfc,
                          const float* __restrict__ bfc, float* __restrict__ out) {
  const unsigned short* h = (const unsigned short*)(ws + OFF_H1);  // t=254 writes h1
  int o = threadIdx.x & 127;
  int b = blockIdx.x * 2 + (threadIdx.x >> 7);
  const float* wrow = Wfc + (size_t)o * 1024;
  float acc = bfc[o];
  int gb = b >> 7, rb = b & 127;
#pragma unroll 4
  for (int k = 0; k < 1024; k += 8) {
    ushort8 hv = *(const ushort8*)&h[((size_t)(gb * 64 + (k >> 4)) * 128 + rb) * 16 + (k & 15)];
    f4 w0 = *(const f4*)&wrow[k];
    f4 w1 = *(const f4*)&wrow[k + 4];
#pragma unroll
    for (int j = 0; j < 4; j++) acc += h2f(hv[j]) * w0[j];
#pragma unroll
    for (int j = 0; j < 4; j++) acc += h2f(hv[4 + j]) * w1[j];
  }
  out[(size_t)b * 128 + o] = acc;
}

extern "C" void kernel_launch(void* const* d_in, const int* in_sizes, int n_in,
                              void* d_out, int out_size, void* d_ws, size_t ws_size,
                              hipStream_t stream) {
  const float* x   = (const float*)d_in[0];
  const float* Wih = (const float*)d_in[1];
  const float* Whh = (const float*)d_in[2];
  const float* bih = (const float*)d_in[3];
  const float* bhh = (const float*)d_in[4];
  const float* Wfc = (const float*)d_in[5];
  const float* bfc = (const float*)d_in[6];
  char* ws = (char*)d_ws;

  hipMemsetAsync(ws + OFF_H0, 0, ((size_t)1 << 20) + 4096, stream);
  prep_wcat<<<2320, 256, 0, stream>>>(Wih, Whh, bih, bhh, ws);
  prep_xt<<<2048, 256, 0, stream>>>(x, ws);
  lstm_persist<<<256, 512, 0, stream>>>(ws);
  fc_kernel<<<256, 256, 0, stream>>>(ws, Wfc, bfc, (float*)d_out);
}